// Round 25
// baseline (141.696 us; speedup 1.0000x reference)
//
#include <hip/hip_runtime.h>
#include <hip/hip_bf16.h>
#include <stdint.h>

#define Bn  2
#define Tn  2048
#define Dn  1024
#define Hn  16
#define DHn 64
#define Mn  (Bn*Tn)

typedef __attribute__((ext_vector_type(8))) short short8;
typedef __attribute__((ext_vector_type(4))) short short4v;
typedef __attribute__((ext_vector_type(4))) float f32x4;

__device__ __forceinline__ f32x4 fzero4() { f32x4 z = {0.f, 0.f, 0.f, 0.f}; return z; }

#define TR16(dst, a32) asm volatile("ds_read_b64_tr_b16 %0, %1" : "=v"(dst) : "v"(a32))
#define EXP2(x) __builtin_amdgcn_exp2f(x)     // raw v_exp_f32 (args bounded <=0)

__device__ __forceinline__ short8 cvt8(const float4& a, const float4& b) {
    union { __hip_bfloat16 h[8]; short8 u; } w;
    w.h[0] = __float2bfloat16(a.x); w.h[1] = __float2bfloat16(a.y);
    w.h[2] = __float2bfloat16(a.z); w.h[3] = __float2bfloat16(a.w);
    w.h[4] = __float2bfloat16(b.x); w.h[5] = __float2bfloat16(b.y);
    w.h[6] = __float2bfloat16(b.z); w.h[7] = __float2bfloat16(b.w);
    return w.u;
}

// ---------------- f32 -> bf16 for wq/wk/wv ----------------
__global__ void cvt3_kernel(const float* __restrict__ a0, const float* __restrict__ a1,
                            const float* __restrict__ a2,
                            __hip_bfloat16* __restrict__ o0, __hip_bfloat16* __restrict__ o1,
                            __hip_bfloat16* __restrict__ o2, int n)
{
    const int i = (blockIdx.x * blockDim.x + threadIdx.x) * 8;
    if (i >= n) return;
    const float* in = blockIdx.y == 0 ? a0 : (blockIdx.y == 1 ? a1 : a2);
    __hip_bfloat16* out = blockIdx.y == 0 ? o0 : (blockIdx.y == 1 ? o1 : o2);
    float4 a = *(const float4*)(in + i);
    float4 b = *(const float4*)(in + i + 4);
    *(short8*)(out + i) = cvt8(a, b);
}

// ---------------- fused QKV projection GEMM: 64x128 tile, (256,4) -----------
// A = f32 input, cvt fused into reg-staging; B = bf16 via global_load_lds.
// grp==0 (Q) output PRE-SCALED by log2(e)/sqrt(DH): softmax in log2 domain.
__global__ __launch_bounds__(256, 4)
void gemm_qkv_kernel(const float* __restrict__ qa, const float* __restrict__ ka,
                     const float* __restrict__ va,
                     const __hip_bfloat16* __restrict__ wq, const __hip_bfloat16* __restrict__ wk,
                     const __hip_bfloat16* __restrict__ wv,
                     const float* __restrict__ bq_, const float* __restrict__ bk_,
                     const float* __restrict__ bv_,
                     __hip_bfloat16* __restrict__ Qp, __hip_bfloat16* __restrict__ Kp,
                     __hip_bfloat16* __restrict__ Vp)
{
    __shared__ alignas(16) short As[2][64*32];
    __shared__ alignas(16) short Bs[2][128*32];
    const int grp = blockIdx.y >> 3;
    const float* A           = grp == 0 ? qa : (grp == 1 ? ka : va);
    const __hip_bfloat16* Bw = grp == 0 ? wq : (grp == 1 ? wk : wv);
    const float* bias        = grp == 0 ? bq_ : (grp == 1 ? bk_ : bv_);
    __hip_bfloat16* C        = grp == 0 ? Qp : (grp == 1 ? Kp : Vp);
    const float scl          = grp == 0 ? 0.18033688011112042f : 1.0f;

    const int t = threadIdx.x, lane = t & 63, wave = t >> 6;
    const int wm = wave >> 1, wn = wave & 1;
    const int row0 = blockIdx.x * 64, col0 = (blockIdx.y & 7) * 128;

    f32x4 acc[2][4];
#pragma unroll
    for (int m = 0; m < 2; ++m)
#pragma unroll
        for (int n = 0; n < 4; ++n) acc[m][n] = fzero4();

    const int srow = wave*16 + (lane >> 2);
    const int skk  = (lane & 3) * 8;
    const int ldsb = wave * 1024 + (lane & 63) * 16;

    float4 ra[2];
    auto LOAD_A = [&](int k0) {
        const float* ap = A + (size_t)(row0 + srow)*Dn + k0 + skk;
        ra[0] = *(const float4*)ap;
        ra[1] = *(const float4*)(ap + 4);
    };
    auto WRITE_A = [&](int buf) {
        *(short8*)((char*)As[buf] + ldsb) = cvt8(ra[0], ra[1]);
    };
    auto STAGE_B = [&](int buf, int k0) {
#pragma unroll
        for (int i = 0; i < 2; ++i)
            __builtin_amdgcn_global_load_lds(
                (const __attribute__((address_space(1))) void*)(Bw + (size_t)(col0 + i*64 + srow)*Dn + k0 + skk),
                (__attribute__((address_space(3))) void*)((char*)Bs[buf] + i*4096 + ldsb), 16, 0, 0);
    };

    LOAD_A(0);
    STAGE_B(0, 0);
    WRITE_A(0);
    __syncthreads();
    int cur = 0;
    for (int k0 = 0; k0 < Dn; k0 += 32) {
        const bool more = (k0 + 32 < Dn);
        if (more) { LOAD_A(k0 + 32); STAGE_B(cur ^ 1, k0 + 32); }
        short8 af[2], bf_[4];
#pragma unroll
        for (int m = 0; m < 2; ++m)
            af[m] = *(const short8*)((char*)As[cur] + (wm*32 + m*16 + (lane & 15))*64 + (lane >> 4)*16);
#pragma unroll
        for (int n = 0; n < 4; ++n)
            bf_[n] = *(const short8*)((char*)Bs[cur] + (wn*64 + n*16 + (lane & 15))*64 + (lane >> 4)*16);
        __builtin_amdgcn_s_setprio(1);
#pragma unroll
        for (int m = 0; m < 2; ++m)
#pragma unroll
            for (int n = 0; n < 4; ++n)
                acc[m][n] = __builtin_amdgcn_mfma_f32_16x16x32_bf16(af[m], bf_[n], acc[m][n], 0, 0, 0);
        __builtin_amdgcn_s_setprio(0);
        __builtin_amdgcn_sched_barrier(0);
        if (more) WRITE_A(cur ^ 1);
        __syncthreads();
        cur ^= 1;
    }

#pragma unroll
    for (int n = 0; n < 4; ++n) {
        const int col = col0 + wn*64 + n*16 + (lane & 15);
        const float bv = bias[col];
#pragma unroll
        for (int m = 0; m < 2; ++m) {
            const int rb_ = row0 + wm*32 + m*16 + (lane>>4)*4;
#pragma unroll
            for (int i = 0; i < 4; ++i)
                C[(size_t)(rb_+i)*Dn + col] = __float2bfloat16((acc[m][n][i] + bv) * scl);
        }
    }
}

// ---------------- final GEMM: 64x128 tile, bf16 A+B via global_load_lds -----
__global__ __launch_bounds__(256, 4)
void gemm_out_kernel(const __hip_bfloat16* __restrict__ A,
                     const __hip_bfloat16* __restrict__ Bw,
                     const float* __restrict__ bias,
                     float* __restrict__ C)
{
    __shared__ alignas(16) short As[2][64*32];
    __shared__ alignas(16) short Bs[2][128*32];
    const int t = threadIdx.x, lane = t & 63, wave = t >> 6;
    const int wm = wave >> 1, wn = wave & 1;
    const int row0 = blockIdx.x * 64, col0 = blockIdx.y * 128;

    f32x4 acc[2][4];
#pragma unroll
    for (int m = 0; m < 2; ++m)
#pragma unroll
        for (int n = 0; n < 4; ++n) acc[m][n] = fzero4();

    const int srow = wave*16 + (lane >> 2);
    const int skk  = (lane & 3) * 8;
    const int ldsb = wave * 1024;

    auto STAGE = [&](int buf, int k0) {
        __builtin_amdgcn_global_load_lds(
            (const __attribute__((address_space(1))) void*)(A + (size_t)(row0 + srow)*Dn + k0 + skk),
            (__attribute__((address_space(3))) void*)((char*)As[buf] + ldsb), 16, 0, 0);
#pragma unroll
        for (int i = 0; i < 2; ++i)
            __builtin_amdgcn_global_load_lds(
                (const __attribute__((address_space(1))) void*)(Bw + (size_t)(col0 + i*64 + srow)*Dn + k0 + skk),
                (__attribute__((address_space(3))) void*)((char*)Bs[buf] + i*4096 + ldsb), 16, 0, 0);
    };

    STAGE(0, 0);
    __syncthreads();
    int cur = 0;
    for (int k0 = 0; k0 < Dn; k0 += 32) {
        if (k0 + 32 < Dn) STAGE(cur ^ 1, k0 + 32);
        short8 af[2], bf_[4];
#pragma unroll
        for (int m = 0; m < 2; ++m)
            af[m] = *(const short8*)((char*)As[cur] + (wm*32 + m*16 + (lane & 15))*64 + (lane >> 4)*16);
#pragma unroll
        for (int n = 0; n < 4; ++n)
            bf_[n] = *(const short8*)((char*)Bs[cur] + (wn*64 + n*16 + (lane & 15))*64 + (lane >> 4)*16);
        __builtin_amdgcn_s_setprio(1);
#pragma unroll
        for (int m = 0; m < 2; ++m)
#pragma unroll
            for (int n = 0; n < 4; ++n)
                acc[m][n] = __builtin_amdgcn_mfma_f32_16x16x32_bf16(af[m], bf_[n], acc[m][n], 0, 0, 0);
        __builtin_amdgcn_s_setprio(0);
        __syncthreads();
        cur ^= 1;
    }

#pragma unroll
    for (int n = 0; n < 4; ++n) {
        const int col = col0 + wn*64 + n*16 + (lane & 15);
        const float bv = bias[col];
#pragma unroll
        for (int m = 0; m < 2; ++m) {
            const int rb_ = row0 + wm*32 + m*16 + (lane>>4)*4;
#pragma unroll
            for (int i = 0; i < 4; ++i)
                C[(size_t)(rb_+i)*Dn + col] = acc[m][n][i] + bv;
        }
    }
}

// ---------------- flash attention fwd: split-kv wave pairs (r14 structure) ---
// wo f32->bf16 fused in preamble; all exp2 via raw v_exp_f32.
#define VPL 1288

__global__ __launch_bounds__(256, 2)
void attn_kernel(const __hip_bfloat16* __restrict__ Q,
                 const __hip_bfloat16* __restrict__ K,
                 const __hip_bfloat16* __restrict__ V,
                 __hip_bfloat16* __restrict__ O,
                 const float* __restrict__ wo_src,
                 __hip_bfloat16* __restrict__ wo_dst)
{
    __shared__ alignas(16) short Vlds[2*2*4*VPL];
    const int t = threadIdx.x, lane = t & 63, wave = t >> 6;

    {   // fused wo conversion (one short8 per thread), hidden under main loop
        const int off = (blockIdx.x * 256 + t) * 8;
        float4 a = *(const float4*)(wo_src + off);
        float4 b2 = *(const float4*)(wo_src + off + 4);
        *(short8*)(wo_dst + off) = cvt8(a, b2);
    }

    const int g = lane >> 4, c = lane & 15;
    const int pk = wave & 1, qh = wave >> 1;
    const int blk = (blockIdx.x & 7) * 64 + (blockIdx.x >> 3);   // XCD swizzle
    const int qb = blk & 15;
    const int h  = (blk >> 4) & (Hn - 1);
    const int b  = blk >> 8;
    const size_t base = (size_t)b * Tn * Dn + (size_t)h * DHn;
    const int q0 = qb * 128 + qh * 64;

    short8 bq[4][2];
#pragma unroll
    for (int qs = 0; qs < 4; ++qs) {
        const __hip_bfloat16* qp = Q + base + (size_t)(q0 + qs*16 + c) * Dn + g*8;
        bq[qs][0] = *(const short8*)qp;
        bq[qs][1] = *(const short8*)(qp + 32);
    }
    short8 ones;
#pragma unroll
    for (int i = 0; i < 8; ++i) ones[i] = (short)0x3F80;

    f32x4 o_[4][4];
#pragma unroll
    for (int qs = 0; qs < 4; ++qs)
#pragma unroll
        for (int d = 0; d < 4; ++d) o_[qs][d] = fzero4();
    float m_[4] = {-3e38f, -3e38f, -3e38f, -3e38f};
    f32x4 lacc[4] = {fzero4(), fzero4(), fzero4(), fzero4()};

    const int vrow = t >> 3;
    const int vd0  = ((t>>1)&3)*VPL + (vrow>>2)*80 + (vrow&3)*16 + (t&1)*8;
    const int vcol = (((t>>1)&3)*16 + (t&1)*8);
    const uint32_t vbase = (uint32_t)(uintptr_t)(void*)Vlds;
    const uint32_t atr = vbase + (uint32_t)(pk*10304 + g*160 + c*8);

    short8 akA[4][2], akB[4][2];
    {
        const __hip_bfloat16* kp = K + base + (size_t)(pk*64 + c) * Dn + g*8;
#pragma unroll
        for (int sub = 0; sub < 4; ++sub)
#pragma unroll
            for (int ks = 0; ks < 2; ++ks)
                akA[sub][ks] = *(const short8*)(kp + (size_t)sub*16*Dn + ks*32);
    }

    auto ITER = [&](const short8 (&ck)[4][2], short8 (&nk)[4][2], int it) {
        const int kv0 = it * 128;
        short8 cv[2][2];
#pragma unroll
        for (int p = 0; p < 2; ++p) {
            const __hip_bfloat16* vp = V + base + (size_t)(kv0 + p*64 + vrow) * Dn + vcol;
            cv[p][0] = *(const short8*)vp;
            cv[p][1] = *(const short8*)(vp + (size_t)32*Dn);
        }
        {
            const int kvn = (it < 15) ? kv0 + 128 + pk*64 : pk*64;
            const __hip_bfloat16* kp = K + base + (size_t)(kvn + c) * Dn + g*8;
#pragma unroll
            for (int sub = 0; sub < 4; ++sub)
#pragma unroll
                for (int ks = 0; ks < 2; ++ks)
                    nk[sub][ks] = *(const short8*)(kp + (size_t)sub*16*Dn + ks*32);
        }

        short8 pa[4][2];
#pragma unroll
        for (int qs = 0; qs < 4; ++qs) {
            f32x4 s_[4];
#pragma unroll
            for (int sub = 0; sub < 4; ++sub) s_[sub] = fzero4();
            __builtin_amdgcn_s_setprio(1);
#pragma unroll
            for (int sub = 0; sub < 4; ++sub)
#pragma unroll
                for (int ks = 0; ks < 2; ++ks)
                    s_[sub] = __builtin_amdgcn_mfma_f32_16x16x32_bf16(
                        ck[sub][ks], bq[qs][ks], s_[sub], 0, 0, 0);
            __builtin_amdgcn_s_setprio(0);

            float r0 = fmaxf(fmaxf(s_[0][0], s_[0][1]), fmaxf(s_[0][2], s_[0][3]));
            float r1 = fmaxf(fmaxf(s_[1][0], s_[1][1]), fmaxf(s_[1][2], s_[1][3]));
            float r2 = fmaxf(fmaxf(s_[2][0], s_[2][1]), fmaxf(s_[2][2], s_[2][3]));
            float r3 = fmaxf(fmaxf(s_[3][0], s_[3][1]), fmaxf(s_[3][2], s_[3][3]));
            float rm = fmaxf(fmaxf(r0, r1), fmaxf(r2, r3));
            if (!__all(rm - m_[qs] <= 8.0f)) {      // log2 domain (Q pre-scaled)
                float gm = fmaxf(rm, __shfl_xor(rm, 16));
                gm = fmaxf(gm, __shfl_xor(gm, 32));
                const float mn = fmaxf(m_[qs], gm);
                const float sc = EXP2(m_[qs] - mn);
                m_[qs] = mn;
                lacc[qs][0] *= sc;
#pragma unroll
                for (int d = 0; d < 4; ++d)
#pragma unroll
                    for (int i = 0; i < 4; ++i) o_[qs][d][i] *= sc;
            }
            const float mn = m_[qs];
#pragma unroll
            for (int kc = 0; kc < 2; ++kc)
#pragma unroll
                for (int hf = 0; hf < 2; ++hf)
#pragma unroll
                    for (int i = 0; i < 4; ++i) {
                        const float p = EXP2(s_[kc*2+hf][i] - mn);
                        union { __hip_bfloat16 hb; short u; } cvp;
                        cvp.hb = __float2bfloat16(p);
                        pa[qs][kc][hf*4 + i] = cvp.u;
                    }
            lacc[qs] = __builtin_amdgcn_mfma_f32_16x16x32_bf16(ones, pa[qs][0], lacc[qs], 0, 0, 0);
            lacc[qs] = __builtin_amdgcn_mfma_f32_16x16x32_bf16(ones, pa[qs][1], lacc[qs], 0, 0, 0);
        }

        short* vb = Vlds + (it & 1) * 10304;
#pragma unroll
        for (int p = 0; p < 2; ++p) {
            *(short8*)(vb + p*5152 + vd0)       = cv[p][0];
            *(short8*)(vb + p*5152 + vd0 + 640) = cv[p][1];
        }
        asm volatile("s_waitcnt lgkmcnt(0)" ::: "memory");
        __builtin_amdgcn_s_barrier();
        __builtin_amdgcn_sched_barrier(0);

        const uint32_t atrb = atr + (uint32_t)((it & 1) * 20608u);
        short4v tv[4][2][2];
#pragma unroll
        for (int d = 0; d < 4; ++d)
#pragma unroll
            for (int kc = 0; kc < 2; ++kc) {
                const uint32_t a = atrb + (uint32_t)(d*2576 + kc*1280);
                TR16(tv[d][kc][0], a);
                TR16(tv[d][kc][1], a + 640);
            }
#pragma unroll
        for (int d = 0; d < 4; ++d) {
            if (d == 0)      asm volatile("s_waitcnt lgkmcnt(12)" ::: "memory");
            else if (d == 1) asm volatile("s_waitcnt lgkmcnt(8)" ::: "memory");
            else if (d == 2) asm volatile("s_waitcnt lgkmcnt(4)" ::: "memory");
            else             asm volatile("s_waitcnt lgkmcnt(0)" ::: "memory");
            __builtin_amdgcn_sched_barrier(0);
            const short8 av0 = __builtin_shufflevector(tv[d][0][0], tv[d][0][1], 0,1,2,3,4,5,6,7);
            const short8 av1 = __builtin_shufflevector(tv[d][1][0], tv[d][1][1], 0,1,2,3,4,5,6,7);
            __builtin_amdgcn_s_setprio(1);
#pragma unroll
            for (int qs = 0; qs < 4; ++qs) {
                o_[qs][d] = __builtin_amdgcn_mfma_f32_16x16x32_bf16(av0, pa[qs][0], o_[qs][d], 0, 0, 0);
                o_[qs][d] = __builtin_amdgcn_mfma_f32_16x16x32_bf16(av1, pa[qs][1], o_[qs][d], 0, 0, 0);
            }
            __builtin_amdgcn_s_setprio(0);
        }
    };

    for (int j = 0; j < 8; ++j) {
        ITER(akA, akB, 2*j);
        ITER(akB, akA, 2*j + 1);
    }

    // ---- flash-combine epilogue ----
    __syncthreads();
    float* cbase = (float*)Vlds;
    if (pk == 1) {
        float* cb = cbase + qh * 4608;
#pragma unroll
        for (int qs = 0; qs < 4; ++qs)
#pragma unroll
            for (int d = 0; d < 4; ++d)
                *(f32x4*)(cb + ((qs*4 + d)*64 + lane)*4) = o_[qs][d];
#pragma unroll
        for (int qs = 0; qs < 4; ++qs) {
            cb[4096 + qs*64 + lane] = m_[qs];
            cb[4352 + qs*64 + lane] = lacc[qs][0];
        }
    }
    __syncthreads();
    if (pk == 0) {
        float* cb = cbase + qh * 4608;
#pragma unroll
        for (int qs = 0; qs < 4; ++qs) {
            const float m1 = cb[4096 + qs*64 + lane];
            const float l1 = cb[4352 + qs*64 + lane];
            const float mN = fmaxf(m_[qs], m1);
            const float sc0 = EXP2(m_[qs] - mN);
            const float sc1 = EXP2(m1 - mN);
            const float inv = 1.f / (lacc[qs][0]*sc0 + l1*sc1);
            __hip_bfloat16* op = O + base + (size_t)(q0 + qs*16 + c) * Dn + g*4;
#pragma unroll
            for (int d = 0; d < 4; ++d) {
                const f32x4 o1 = *(const f32x4*)(cb + ((qs*4 + d)*64 + lane)*4);
                union { __hip_bfloat16 hb[4]; ushort4 u4; } w;
#pragma unroll
                for (int i = 0; i < 4; ++i)
                    w.hb[i] = __float2bfloat16((o_[qs][d][i]*sc0 + o1[i]*sc1) * inv);
                *(ushort4*)(op + d*16) = w.u4;
            }
        }
    }
}

extern "C" void kernel_launch(void* const* d_in, const int* in_sizes, int n_in,
                              void* d_out, int out_size, void* d_ws, size_t ws_size,
                              hipStream_t stream)
{
    (void)in_sizes; (void)n_in; (void)out_size; (void)ws_size;
    const float* q    = (const float*)d_in[0];
    const float* k    = (const float*)d_in[1];
    const float* v    = (const float*)d_in[2];
    const float* wq_w = (const float*)d_in[3];
    const float* wq_b = (const float*)d_in[4];
    const float* wk_w = (const float*)d_in[5];
    const float* wk_b = (const float*)d_in[6];
    const float* wv_w = (const float*)d_in[7];
    const float* wv_b = (const float*)d_in[8];
    const float* wo_w = (const float*)d_in[9];
    const float* wo_b = (const float*)d_in[10];

    char* ws = (char*)d_ws;
    const size_t W  = (size_t)Dn * Dn * 2;   // 2 MiB
    const size_t S1 = (size_t)Mn * Dn * 2;   // 8 MiB
    __hip_bfloat16* wqb = (__hip_bfloat16*)(ws);
    __hip_bfloat16* wkb = (__hip_bfloat16*)(ws + W);
    __hip_bfloat16* wvb = (__hip_bfloat16*)(ws + 2*W);
    __hip_bfloat16* wob = (__hip_bfloat16*)(ws + 3*W);
    __hip_bfloat16* Qp  = (__hip_bfloat16*)(ws + 4*W);
    __hip_bfloat16* Kp  = (__hip_bfloat16*)(ws + 4*W + S1);
    __hip_bfloat16* Vp  = (__hip_bfloat16*)(ws + 4*W + 2*S1);
    __hip_bfloat16* Ap  = (__hip_bfloat16*)(ws + 4*W + 3*S1);

    const int nW = Dn * Dn;
    cvt3_kernel<<<dim3(nW/2048, 3), 256, 0, stream>>>(wq_w, wk_w, wv_w, wqb, wkb, wvb, nW);

    gemm_qkv_kernel<<<dim3(Mn/64, 24), 256, 0, stream>>>(
        q, k, v, wqb, wkb, wvb, wq_b, wk_b, wv_b, Qp, Kp, Vp);

    attn_kernel<<<Bn*Hn*(Tn/128), 256, 0, stream>>>(Qp, Kp, Vp, Ap, wo_w, wob);

    gemm_out_kernel<<<dim3(Mn/64, Dn/128), 256, 0, stream>>>(Ap, wob, wo_b, (float*)d_out);
}

// Round 26
// 120.759 us; speedup vs baseline: 1.1734x; 1.1734x over previous
//
#include <hip/hip_runtime.h>
#include <hip/hip_bf16.h>
#include <stdint.h>

#define Bn  2
#define Tn  2048
#define Dn  1024
#define Hn  16
#define DHn 64
#define Mn  (Bn*Tn)

typedef __attribute__((ext_vector_type(8))) short short8;
typedef __attribute__((ext_vector_type(4))) short short4v;
typedef __attribute__((ext_vector_type(4))) float f32x4;

__device__ __forceinline__ f32x4 fzero4() { f32x4 z = {0.f, 0.f, 0.f, 0.f}; return z; }

#define TR16(dst, a32) asm volatile("ds_read_b64_tr_b16 %0, %1" : "=v"(dst) : "v"(a32))
#define EXP2(x) __builtin_amdgcn_exp2f(x)     // raw v_exp_f32 (args bounded <=0)

__device__ __forceinline__ short8 cvt8(const float4& a, const float4& b) {
    union { __hip_bfloat16 h[8]; short8 u; } w;
    w.h[0] = __float2bfloat16(a.x); w.h[1] = __float2bfloat16(a.y);
    w.h[2] = __float2bfloat16(a.z); w.h[3] = __float2bfloat16(a.w);
    w.h[4] = __float2bfloat16(b.x); w.h[5] = __float2bfloat16(b.y);
    w.h[6] = __float2bfloat16(b.z); w.h[7] = __float2bfloat16(b.w);
    return w.u;
}

// ---------------- f32 -> bf16 for wq/wk/wv ----------------
__global__ void cvt3_kernel(const float* __restrict__ a0, const float* __restrict__ a1,
                            const float* __restrict__ a2,
                            __hip_bfloat16* __restrict__ o0, __hip_bfloat16* __restrict__ o1,
                            __hip_bfloat16* __restrict__ o2, int n)
{
    const int i = (blockIdx.x * blockDim.x + threadIdx.x) * 8;
    if (i >= n) return;
    const float* in = blockIdx.y == 0 ? a0 : (blockIdx.y == 1 ? a1 : a2);
    __hip_bfloat16* out = blockIdx.y == 0 ? o0 : (blockIdx.y == 1 ? o1 : o2);
    float4 a = *(const float4*)(in + i);
    float4 b = *(const float4*)(in + i + 4);
    *(short8*)(out + i) = cvt8(a, b);
}

// ---------------- fused QKV projection GEMM (A = f32 in, cvt fused) ----------
// grp==0 (Q) output PRE-SCALED by log2(e)/sqrt(DH): softmax in log2 domain.
__global__ __launch_bounds__(256, 3)
void gemm_qkv_kernel(const float* __restrict__ qa, const float* __restrict__ ka,
                     const float* __restrict__ va,
                     const __hip_bfloat16* __restrict__ wq, const __hip_bfloat16* __restrict__ wk,
                     const __hip_bfloat16* __restrict__ wv,
                     const float* __restrict__ bq_, const float* __restrict__ bk_,
                     const float* __restrict__ bv_,
                     __hip_bfloat16* __restrict__ Qp, __hip_bfloat16* __restrict__ Kp,
                     __hip_bfloat16* __restrict__ Vp)
{
    __shared__ alignas(16) short As[2][128*32];
    __shared__ alignas(16) short Bs[2][128*32];
    const int grp = blockIdx.y >> 3;
    const float* A           = grp == 0 ? qa : (grp == 1 ? ka : va);
    const __hip_bfloat16* Bw = grp == 0 ? wq : (grp == 1 ? wk : wv);
    const float* bias        = grp == 0 ? bq_ : (grp == 1 ? bk_ : bv_);
    __hip_bfloat16* C        = grp == 0 ? Qp : (grp == 1 ? Kp : Vp);
    const float scl          = grp == 0 ? 0.18033688011112042f : 1.0f;

    const int t = threadIdx.x, lane = t & 63, wave = t >> 6;
    const int wm = wave >> 1, wn = wave & 1;
    const int row0 = blockIdx.x * 128, col0 = (blockIdx.y & 7) * 128;

    f32x4 acc[4][4];
#pragma unroll
    for (int m = 0; m < 4; ++m)
#pragma unroll
        for (int n = 0; n < 4; ++n) acc[m][n] = fzero4();

    const int srow = wave*16 + (lane >> 2);
    const int skk  = (lane & 3) * 8;
    const int ldsb = wave * 1024 + (lane & 63) * 16;

    float4 ra[2][2];
    auto LOAD_A = [&](int k0) {
#pragma unroll
        for (int i = 0; i < 2; ++i) {
            const float* ap = A + (size_t)(row0 + i*64 + srow)*Dn + k0 + skk;
            ra[i][0] = *(const float4*)ap;
            ra[i][1] = *(const float4*)(ap + 4);
        }
    };
    auto WRITE_A = [&](int buf) {
#pragma unroll
        for (int i = 0; i < 2; ++i)
            *(short8*)((char*)As[buf] + i*4096 + ldsb) = cvt8(ra[i][0], ra[i][1]);
    };
    auto STAGE_B = [&](int buf, int k0) {
#pragma unroll
        for (int i = 0; i < 2; ++i)
            __builtin_amdgcn_global_load_lds(
                (const __attribute__((address_space(1))) void*)(Bw + (size_t)(col0 + i*64 + srow)*Dn + k0 + skk),
                (__attribute__((address_space(3))) void*)((char*)Bs[buf] + i*4096 + wave*1024 + (lane&63)*16), 16, 0, 0);
    };

    LOAD_A(0);
    STAGE_B(0, 0);
    WRITE_A(0);
    __syncthreads();
    int cur = 0;
    for (int k0 = 0; k0 < Dn; k0 += 32) {
        const bool more = (k0 + 32 < Dn);
        if (more) { LOAD_A(k0 + 32); STAGE_B(cur ^ 1, k0 + 32); }
        short8 af[4], bf_[4];
#pragma unroll
        for (int m = 0; m < 4; ++m)
            af[m] = *(const short8*)((char*)As[cur] + (wm*64 + m*16 + (lane & 15))*64 + (lane >> 4)*16);
#pragma unroll
        for (int n = 0; n < 4; ++n)
            bf_[n] = *(const short8*)((char*)Bs[cur] + (wn*64 + n*16 + (lane & 15))*64 + (lane >> 4)*16);
        __builtin_amdgcn_s_setprio(1);
#pragma unroll
        for (int m = 0; m < 4; ++m)
#pragma unroll
            for (int n = 0; n < 4; ++n)
                acc[m][n] = __builtin_amdgcn_mfma_f32_16x16x32_bf16(af[m], bf_[n], acc[m][n], 0, 0, 0);
        __builtin_amdgcn_s_setprio(0);
        __builtin_amdgcn_sched_barrier(0);
        if (more) WRITE_A(cur ^ 1);
        __syncthreads();
        cur ^= 1;
    }

#pragma unroll
    for (int n = 0; n < 4; ++n) {
        const int col = col0 + wn*64 + n*16 + (lane & 15);
        const float bv = bias[col];
#pragma unroll
        for (int m = 0; m < 4; ++m) {
            const int rb_ = row0 + wm*64 + m*16 + (lane>>4)*4;
#pragma unroll
            for (int i = 0; i < 4; ++i)
                C[(size_t)(rb_+i)*Dn + col] = __float2bfloat16((acc[m][n][i] + bv) * scl);
        }
    }
}

// ---------------- final GEMM: 64x128 tile, bf16 A+B via global_load_lds -----
__global__ __launch_bounds__(256, 4)
void gemm_out_kernel(const __hip_bfloat16* __restrict__ A,
                     const __hip_bfloat16* __restrict__ Bw,
                     const float* __restrict__ bias,
                     float* __restrict__ C)
{
    __shared__ alignas(16) short As[2][64*32];
    __shared__ alignas(16) short Bs[2][128*32];
    const int t = threadIdx.x, lane = t & 63, wave = t >> 6;
    const int wm = wave >> 1, wn = wave & 1;
    const int row0 = blockIdx.x * 64, col0 = blockIdx.y * 128;

    f32x4 acc[2][4];
#pragma unroll
    for (int m = 0; m < 2; ++m)
#pragma unroll
        for (int n = 0; n < 4; ++n) acc[m][n] = fzero4();

    const int srow = wave*16 + (lane >> 2);
    const int skk  = (lane & 3) * 8;
    const int ldsb = wave * 1024;

    auto STAGE = [&](int buf, int k0) {
        __builtin_amdgcn_global_load_lds(
            (const __attribute__((address_space(1))) void*)(A + (size_t)(row0 + srow)*Dn + k0 + skk),
            (__attribute__((address_space(3))) void*)((char*)As[buf] + ldsb), 16, 0, 0);
#pragma unroll
        for (int i = 0; i < 2; ++i)
            __builtin_amdgcn_global_load_lds(
                (const __attribute__((address_space(1))) void*)(Bw + (size_t)(col0 + i*64 + srow)*Dn + k0 + skk),
                (__attribute__((address_space(3))) void*)((char*)Bs[buf] + i*4096 + ldsb), 16, 0, 0);
    };

    STAGE(0, 0);
    __syncthreads();
    int cur = 0;
    for (int k0 = 0; k0 < Dn; k0 += 32) {
        if (k0 + 32 < Dn) STAGE(cur ^ 1, k0 + 32);
        short8 af[2], bf_[4];
#pragma unroll
        for (int m = 0; m < 2; ++m)
            af[m] = *(const short8*)((char*)As[cur] + (wm*32 + m*16 + (lane & 15))*64 + (lane >> 4)*16);
#pragma unroll
        for (int n = 0; n < 4; ++n)
            bf_[n] = *(const short8*)((char*)Bs[cur] + (wn*64 + n*16 + (lane & 15))*64 + (lane >> 4)*16);
        __builtin_amdgcn_s_setprio(1);
#pragma unroll
        for (int m = 0; m < 2; ++m)
#pragma unroll
            for (int n = 0; n < 4; ++n)
                acc[m][n] = __builtin_amdgcn_mfma_f32_16x16x32_bf16(af[m], bf_[n], acc[m][n], 0, 0, 0);
        __builtin_amdgcn_s_setprio(0);
        __syncthreads();
        cur ^= 1;
    }

#pragma unroll
    for (int n = 0; n < 4; ++n) {
        const int col = col0 + wn*64 + n*16 + (lane & 15);
        const float bv = bias[col];
#pragma unroll
        for (int m = 0; m < 2; ++m) {
            const int rb_ = row0 + wm*32 + m*16 + (lane>>4)*4;
#pragma unroll
            for (int i = 0; i < 4; ++i)
                C[(size_t)(rb_+i)*Dn + col] = acc[m][n][i] + bv;
        }
    }
}

// ---------------- flash attention fwd: split-kv wave pairs (r14 structure) ---
// wo f32->bf16 fused in preamble; all exp2 via raw v_exp_f32.
#define VPL 1288

__global__ __launch_bounds__(256, 2)
void attn_kernel(const __hip_bfloat16* __restrict__ Q,
                 const __hip_bfloat16* __restrict__ K,
                 const __hip_bfloat16* __restrict__ V,
                 __hip_bfloat16* __restrict__ O,
                 const float* __restrict__ wo_src,
                 __hip_bfloat16* __restrict__ wo_dst)
{
    __shared__ alignas(16) short Vlds[2*2*4*VPL];
    const int t = threadIdx.x, lane = t & 63, wave = t >> 6;

    {   // fused wo conversion (one short8 per thread), hidden under main loop
        const int off = (blockIdx.x * 256 + t) * 8;
        float4 a = *(const float4*)(wo_src + off);
        float4 b2 = *(const float4*)(wo_src + off + 4);
        *(short8*)(wo_dst + off) = cvt8(a, b2);
    }

    const int g = lane >> 4, c = lane & 15;
    const int pk = wave & 1, qh = wave >> 1;
    const int blk = (blockIdx.x & 7) * 64 + (blockIdx.x >> 3);   // XCD swizzle
    const int qb = blk & 15;
    const int h  = (blk >> 4) & (Hn - 1);
    const int b  = blk >> 8;
    const size_t base = (size_t)b * Tn * Dn + (size_t)h * DHn;
    const int q0 = qb * 128 + qh * 64;

    short8 bq[4][2];
#pragma unroll
    for (int qs = 0; qs < 4; ++qs) {
        const __hip_bfloat16* qp = Q + base + (size_t)(q0 + qs*16 + c) * Dn + g*8;
        bq[qs][0] = *(const short8*)qp;
        bq[qs][1] = *(const short8*)(qp + 32);
    }
    short8 ones;
#pragma unroll
    for (int i = 0; i < 8; ++i) ones[i] = (short)0x3F80;

    f32x4 o_[4][4];
#pragma unroll
    for (int qs = 0; qs < 4; ++qs)
#pragma unroll
        for (int d = 0; d < 4; ++d) o_[qs][d] = fzero4();
    float m_[4] = {-3e38f, -3e38f, -3e38f, -3e38f};
    f32x4 lacc[4] = {fzero4(), fzero4(), fzero4(), fzero4()};

    const int vrow = t >> 3;
    const int vd0  = ((t>>1)&3)*VPL + (vrow>>2)*80 + (vrow&3)*16 + (t&1)*8;
    const int vcol = (((t>>1)&3)*16 + (t&1)*8);
    const uint32_t vbase = (uint32_t)(uintptr_t)(void*)Vlds;
    const uint32_t atr = vbase + (uint32_t)(pk*10304 + g*160 + c*8);

    short8 akA[4][2], akB[4][2];
    {
        const __hip_bfloat16* kp = K + base + (size_t)(pk*64 + c) * Dn + g*8;
#pragma unroll
        for (int sub = 0; sub < 4; ++sub)
#pragma unroll
            for (int ks = 0; ks < 2; ++ks)
                akA[sub][ks] = *(const short8*)(kp + (size_t)sub*16*Dn + ks*32);
    }

    auto ITER = [&](const short8 (&ck)[4][2], short8 (&nk)[4][2], int it) {
        const int kv0 = it * 128;
        short8 cv[2][2];
#pragma unroll
        for (int p = 0; p < 2; ++p) {
            const __hip_bfloat16* vp = V + base + (size_t)(kv0 + p*64 + vrow) * Dn + vcol;
            cv[p][0] = *(const short8*)vp;
            cv[p][1] = *(const short8*)(vp + (size_t)32*Dn);
        }
        {
            const int kvn = (it < 15) ? kv0 + 128 + pk*64 : pk*64;
            const __hip_bfloat16* kp = K + base + (size_t)(kvn + c) * Dn + g*8;
#pragma unroll
            for (int sub = 0; sub < 4; ++sub)
#pragma unroll
                for (int ks = 0; ks < 2; ++ks)
                    nk[sub][ks] = *(const short8*)(kp + (size_t)sub*16*Dn + ks*32);
        }

        short8 pa[4][2];
#pragma unroll
        for (int qs = 0; qs < 4; ++qs) {
            f32x4 s_[4];
#pragma unroll
            for (int sub = 0; sub < 4; ++sub) s_[sub] = fzero4();
            __builtin_amdgcn_s_setprio(1);
#pragma unroll
            for (int sub = 0; sub < 4; ++sub)
#pragma unroll
                for (int ks = 0; ks < 2; ++ks)
                    s_[sub] = __builtin_amdgcn_mfma_f32_16x16x32_bf16(
                        ck[sub][ks], bq[qs][ks], s_[sub], 0, 0, 0);
            __builtin_amdgcn_s_setprio(0);

            float r0 = fmaxf(fmaxf(s_[0][0], s_[0][1]), fmaxf(s_[0][2], s_[0][3]));
            float r1 = fmaxf(fmaxf(s_[1][0], s_[1][1]), fmaxf(s_[1][2], s_[1][3]));
            float r2 = fmaxf(fmaxf(s_[2][0], s_[2][1]), fmaxf(s_[2][2], s_[2][3]));
            float r3 = fmaxf(fmaxf(s_[3][0], s_[3][1]), fmaxf(s_[3][2], s_[3][3]));
            float rm = fmaxf(fmaxf(r0, r1), fmaxf(r2, r3));
            if (!__all(rm - m_[qs] <= 8.0f)) {      // log2 domain (Q pre-scaled)
                float gm = fmaxf(rm, __shfl_xor(rm, 16));
                gm = fmaxf(gm, __shfl_xor(gm, 32));
                const float mn = fmaxf(m_[qs], gm);
                const float sc = EXP2(m_[qs] - mn);
                m_[qs] = mn;
                lacc[qs][0] *= sc;
#pragma unroll
                for (int d = 0; d < 4; ++d)
#pragma unroll
                    for (int i = 0; i < 4; ++i) o_[qs][d][i] *= sc;
            }
            const float mn = m_[qs];
#pragma unroll
            for (int kc = 0; kc < 2; ++kc)
#pragma unroll
                for (int hf = 0; hf < 2; ++hf)
#pragma unroll
                    for (int i = 0; i < 4; ++i) {
                        const float p = EXP2(s_[kc*2+hf][i] - mn);
                        union { __hip_bfloat16 hb; short u; } cvp;
                        cvp.hb = __float2bfloat16(p);
                        pa[qs][kc][hf*4 + i] = cvp.u;
                    }
            lacc[qs] = __builtin_amdgcn_mfma_f32_16x16x32_bf16(ones, pa[qs][0], lacc[qs], 0, 0, 0);
            lacc[qs] = __builtin_amdgcn_mfma_f32_16x16x32_bf16(ones, pa[qs][1], lacc[qs], 0, 0, 0);
        }

        short* vb = Vlds + (it & 1) * 10304;
#pragma unroll
        for (int p = 0; p < 2; ++p) {
            *(short8*)(vb + p*5152 + vd0)       = cv[p][0];
            *(short8*)(vb + p*5152 + vd0 + 640) = cv[p][1];
        }
        asm volatile("s_waitcnt lgkmcnt(0)" ::: "memory");
        __builtin_amdgcn_s_barrier();
        __builtin_amdgcn_sched_barrier(0);

        const uint32_t atrb = atr + (uint32_t)((it & 1) * 20608u);
        short4v tv[4][2][2];
#pragma unroll
        for (int d = 0; d < 4; ++d)
#pragma unroll
            for (int kc = 0; kc < 2; ++kc) {
                const uint32_t a = atrb + (uint32_t)(d*2576 + kc*1280);
                TR16(tv[d][kc][0], a);
                TR16(tv[d][kc][1], a + 640);
            }
#pragma unroll
        for (int d = 0; d < 4; ++d) {
            if (d == 0)      asm volatile("s_waitcnt lgkmcnt(12)" ::: "memory");
            else if (d == 1) asm volatile("s_waitcnt lgkmcnt(8)" ::: "memory");
            else if (d == 2) asm volatile("s_waitcnt lgkmcnt(4)" ::: "memory");
            else             asm volatile("s_waitcnt lgkmcnt(0)" ::: "memory");
            __builtin_amdgcn_sched_barrier(0);
            const short8 av0 = __builtin_shufflevector(tv[d][0][0], tv[d][0][1], 0,1,2,3,4,5,6,7);
            const short8 av1 = __builtin_shufflevector(tv[d][1][0], tv[d][1][1], 0,1,2,3,4,5,6,7);
            __builtin_amdgcn_s_setprio(1);
#pragma unroll
            for (int qs = 0; qs < 4; ++qs) {
                o_[qs][d] = __builtin_amdgcn_mfma_f32_16x16x32_bf16(av0, pa[qs][0], o_[qs][d], 0, 0, 0);
                o_[qs][d] = __builtin_amdgcn_mfma_f32_16x16x32_bf16(av1, pa[qs][1], o_[qs][d], 0, 0, 0);
            }
            __builtin_amdgcn_s_setprio(0);
        }
    };

    for (int j = 0; j < 8; ++j) {
        ITER(akA, akB, 2*j);
        ITER(akB, akA, 2*j + 1);
    }

    // ---- flash-combine epilogue ----
    __syncthreads();
    float* cbase = (float*)Vlds;
    if (pk == 1) {
        float* cb = cbase + qh * 4608;
#pragma unroll
        for (int qs = 0; qs < 4; ++qs)
#pragma unroll
            for (int d = 0; d < 4; ++d)
                *(f32x4*)(cb + ((qs*4 + d)*64 + lane)*4) = o_[qs][d];
#pragma unroll
        for (int qs = 0; qs < 4; ++qs) {
            cb[4096 + qs*64 + lane] = m_[qs];
            cb[4352 + qs*64 + lane] = lacc[qs][0];
        }
    }
    __syncthreads();
    if (pk == 0) {
        float* cb = cbase + qh * 4608;
#pragma unroll
        for (int qs = 0; qs < 4; ++qs) {
            const float m1 = cb[4096 + qs*64 + lane];
            const float l1 = cb[4352 + qs*64 + lane];
            const float mN = fmaxf(m_[qs], m1);
            const float sc0 = EXP2(m_[qs] - mN);
            const float sc1 = EXP2(m1 - mN);
            const float inv = 1.f / (lacc[qs][0]*sc0 + l1*sc1);
            __hip_bfloat16* op = O + base + (size_t)(q0 + qs*16 + c) * Dn + g*4;
#pragma unroll
            for (int d = 0; d < 4; ++d) {
                const f32x4 o1 = *(const f32x4*)(cb + ((qs*4 + d)*64 + lane)*4);
                union { __hip_bfloat16 hb[4]; ushort4 u4; } w;
#pragma unroll
                for (int i = 0; i < 4; ++i)
                    w.hb[i] = __float2bfloat16((o_[qs][d][i]*sc0 + o1[i]*sc1) * inv);
                *(ushort4*)(op + d*16) = w.u4;
            }
        }
    }
}

extern "C" void kernel_launch(void* const* d_in, const int* in_sizes, int n_in,
                              void* d_out, int out_size, void* d_ws, size_t ws_size,
                              hipStream_t stream)
{
    (void)in_sizes; (void)n_in; (void)out_size; (void)ws_size;
    const float* q    = (const float*)d_in[0];
    const float* k    = (const float*)d_in[1];
    const float* v    = (const float*)d_in[2];
    const float* wq_w = (const float*)d_in[3];
    const float* wq_b = (const float*)d_in[4];
    const float* wk_w = (const float*)d_in[5];
    const float* wk_b = (const float*)d_in[6];
    const float* wv_w = (const float*)d_in[7];
    const float* wv_b = (const float*)d_in[8];
    const float* wo_w = (const float*)d_in[9];
    const float* wo_b = (const float*)d_in[10];

    char* ws = (char*)d_ws;
    const size_t W  = (size_t)Dn * Dn * 2;   // 2 MiB
    const size_t S1 = (size_t)Mn * Dn * 2;   // 8 MiB
    __hip_bfloat16* wqb = (__hip_bfloat16*)(ws);
    __hip_bfloat16* wkb = (__hip_bfloat16*)(ws + W);
    __hip_bfloat16* wvb = (__hip_bfloat16*)(ws + 2*W);
    __hip_bfloat16* wob = (__hip_bfloat16*)(ws + 3*W);
    __hip_bfloat16* Qp  = (__hip_bfloat16*)(ws + 4*W);
    __hip_bfloat16* Kp  = (__hip_bfloat16*)(ws + 4*W + S1);
    __hip_bfloat16* Vp  = (__hip_bfloat16*)(ws + 4*W + 2*S1);
    __hip_bfloat16* Ap  = (__hip_bfloat16*)(ws + 4*W + 3*S1);

    const int nW = Dn * Dn;
    cvt3_kernel<<<dim3(nW/2048, 3), 256, 0, stream>>>(wq_w, wk_w, wv_w, wqb, wkb, wvb, nW);

    gemm_qkv_kernel<<<dim3(Mn/128, 24), 256, 0, stream>>>(
        q, k, v, wqb, wkb, wvb, wq_b, wk_b, wv_b, Qp, Kp, Vp);

    attn_kernel<<<Bn*Hn*(Tn/128), 256, 0, stream>>>(Qp, Kp, Vp, Ap, wo_w, wob);

    gemm_out_kernel<<<dim3(Mn/64, Dn/128), 256, 0, stream>>>(Ap, wob, wo_b, (float*)d_out);
}